// Round 6
// baseline (998.668 us; speedup 1.0000x reference)
//
#include <hip/hip_runtime.h>
#include <hip/hip_cooperative_groups.h>

namespace cg = cooperative_groups;

constexpr int NB = 256;   // batch
constexpr int NS = 64;    // seq len
constexpr int NN = 64;    // tree nodes
constexpr int NE = 300;   // embedding dim
constexpr int NH = 600;   // hidden dim

typedef __attribute__((ext_vector_type(8))) short bf16x8;
typedef __attribute__((ext_vector_type(4))) float f32x4;

// ---------------- workspace layout (float-indexed) ----------------
constexpr size_t OFF_H   = 0;                           // h state fp32 [2][NB][NN][NE]
constexpr size_t SZ_H    = (size_t)2*NB*NN*NE;          // 9,830,400
constexpr size_t OFF_T   = OFF_H + SZ_H;                // transformed child rows
constexpr size_t OFF_REP = OFF_T + SZ_H;                // [2][NB][NE]
constexpr size_t SZ_REP  = (size_t)2*NB*NE;
constexpr size_t OFF_WBF = OFF_REP + SZ_REP;            // W_enc bf16 B-frag swizzled
constexpr size_t SZ_WBF  = (size_t)3*20*10*64*8/2;      // 153,600 floats
constexpr size_t OFF_W0T = OFF_WBF + SZ_WBF;            // W0^T [1800][600]
constexpr size_t SZ_W0T  = (size_t)6*NE*NH;
constexpr size_t OFF_W1T = OFF_W0T + SZ_W0T;            // W1^T [600][600]
constexpr size_t SZ_WH   = (size_t)NH*NH;
constexpr size_t OFF_W2T = OFF_W1T + SZ_WH;             // W2^T [600][600]
constexpr size_t OFF_H1  = OFF_W2T + SZ_WH;             // [NB][NH]
constexpr size_t SZ_HB   = (size_t)NB*NH;
constexpr size_t OFF_H2  = OFF_H1 + SZ_HB;
constexpr size_t OFF_H3  = OFF_H2 + SZ_HB;

__device__ __forceinline__ ushort f2bf(float x) {
  unsigned u = __float_as_uint(x);
  unsigned r = (u + 0x7FFFu + ((u >> 16) & 1u)) >> 16;   // RNE
  return (ushort)r;
}

// setup-phase item counts
constexpr int BIAS4 = NB*NH/4;            // 38400 float4 per layer
constexpr int N_BIAS = 3*BIAS4;           // 115200
constexpr int NSWZ = 3*20*10*64;          // 38400 lane-frags
constexpr int NT0 = 1800*600;             // 1,080,000
constexpr int NTH = 600*600;              // 360,000
constexpr int SETUP_ITEMS = N_BIAS + NSWZ + NT0 + 2*NTH;

// FC layer as a device phase: block = 64b x 64j tile, thread = 4b x 4j,
// K split over z-chunks; partials atomicAdd onto bias-initialized out.
// mode 2: build concat feature x on the fly from rep/h; else relu(input).
__device__ __forceinline__ void fc_phase(char* smem, int tid, int bid, int nblk,
    const float* in, const float* __restrict__ WT, float* __restrict__ out,
    int K, int kc, int nz, int mode,
    const float* __restrict__ rep, const float* __restrict__ h) {
  float* xl = (float*)smem;                 // [kc][64 padded to 68]
  int ntiles = 40*nz;
  for (int tt = bid; tt < ntiles; tt += nblk) {
    int b0 = (tt & 3) * 64;
    int j0 = ((tt >> 2) % 10) * 64;
    int k0 = (tt / 40) * kc;
    if (mode == 2) {
      for (int flat = tid; flat < kc*64; flat += 256) {
        int bbp = flat / kc, k = flat % kc;
        int kg = k0 + k, seg = kg / NE, e = kg % NE;
        int b = b0 + bbp;
        float v;
        switch (seg) {
          case 0: v = rep[(size_t)b*NE + e]; break;
          case 1: v = rep[(size_t)(NB+b)*NE + e]; break;
          case 2: v = rep[(size_t)b*NE + e] - rep[(size_t)(NB+b)*NE + e]; break;
          case 3: v = rep[(size_t)b*NE + e] * rep[(size_t)(NB+b)*NE + e]; break;
          case 4: v = h[(size_t)b*NN*NE + e] - h[(size_t)(NB+b)*NN*NE + e]; break;
          default: v = h[(size_t)b*NN*NE + e] * h[(size_t)(NB+b)*NN*NE + e]; break;
        }
        xl[k*68 + bbp] = v;
      }
    } else {
      for (int flat = tid; flat < kc*64; flat += 256) {
        int bbp = flat / kc, k = flat % kc;
        xl[k*68 + bbp] = fmaxf(in[(size_t)(b0+bbp)*K + k0 + k], 0.f);
      }
    }
    __syncthreads();
    int tj = tid & 15, tb = tid >> 4;
    int j = j0 + tj*4;
    if (j + 3 < NH) {
      float acc[4][4];
      #pragma unroll
      for (int a = 0; a < 4; a++)
        #pragma unroll
        for (int bq = 0; bq < 4; bq++) acc[a][bq] = 0.f;
      for (int k = 0; k < kc; k++) {
        const float4 w  = *reinterpret_cast<const float4*>(&WT[(size_t)(k0+k)*NH + j]);
        const float4 xv = *reinterpret_cast<const float4*>(&xl[k*68 + tb*4]);
        acc[0][0] += xv.x*w.x; acc[0][1] += xv.x*w.y; acc[0][2] += xv.x*w.z; acc[0][3] += xv.x*w.w;
        acc[1][0] += xv.y*w.x; acc[1][1] += xv.y*w.y; acc[1][2] += xv.y*w.z; acc[1][3] += xv.y*w.w;
        acc[2][0] += xv.z*w.x; acc[2][1] += xv.z*w.y; acc[2][2] += xv.z*w.z; acc[2][3] += xv.z*w.w;
        acc[3][0] += xv.w*w.x; acc[3][1] += xv.w*w.y; acc[3][2] += xv.w*w.z; acc[3][3] += xv.w*w.w;
      }
      #pragma unroll
      for (int bi = 0; bi < 4; bi++)
        #pragma unroll
        for (int ji = 0; ji < 4; ji++)
          atomicAdd(&out[(size_t)(b0 + tb*4 + bi)*NH + j + ji], acc[bi][ji]);
    }
    __syncthreads();
  }
}

// ---------------- the single cooperative mega-kernel ----------------
// gridDim-agnostic: works at any grid size the driver will co-schedule.
__global__ __launch_bounds__(256, 2)
void k_mega(const int* __restrict__ px, const int* __restrict__ hx,
            const int* __restrict__ pwi, const int* __restrict__ prel,
            const int* __restrict__ hwi, const int* __restrict__ hrel,
            const float* __restrict__ Etab, const float* __restrict__ Wenc,
            const float* __restrict__ W0, const float* __restrict__ b0,
            const float* __restrict__ W1, const float* __restrict__ b1,
            const float* __restrict__ W2, const float* __restrict__ b2,
            const float* __restrict__ Wout, const float* __restrict__ bout,
            float* __restrict__ ws, float* __restrict__ outp) {
  cg::grid_group grid = cg::this_grid();
  __shared__ __align__(16) char smem[61200];
  float*  h   = ws + OFF_H;
  float*  T   = ws + OFF_T;
  float*  rep = ws + OFF_REP;
  ushort* Wbf = (ushort*)(ws + OFF_WBF);
  float*  W0T = ws + OFF_W0T;
  float*  W1T = ws + OFF_W1T;
  float*  W2T = ws + OFF_W2T;
  float*  h1  = ws + OFF_H1;
  float*  h2  = ws + OFF_H2;
  float*  h3  = ws + OFF_H3;
  const int tid  = threadIdx.x;
  const int bid  = blockIdx.x;
  const int nblk = gridDim.x;

  // ===== Phase A: gather (grid-stride over (s,b)) + weight setup ==========
  {
    int* xsh  = (int*)smem;
    int* wish = xsh + 64;
    for (int sb = bid; sb < 2*NB; sb += nblk) {
      int s = sb >> 8, b = sb & 255;
      const int* xs = (s ? hx : px) + b*NS;
      const int* wi = (s ? hwi : pwi) + b*NN;
      __syncthreads();            // protect smem reuse across iterations
      if (tid < NS) xsh[tid] = xs[tid];
      else if (tid < NS + NN) wish[tid - NS] = wi[tid - NS];
      __syncthreads();
      for (int e = tid; e < NE; e += 256) {
        float acc = 0.f;
        #pragma unroll 8
        for (int j = 0; j < NS; j++) acc += Etab[(size_t)xsh[j]*NE + e];
        rep[(size_t)sb*NE + e] = acc;
        size_t hb = (size_t)sb*NN;
        for (int n = 0; n < NN; n++) {
          int w = wish[n];
          h[(hb + n)*NE + e] = (w < 0) ? 1.0f : Etab[(size_t)xsh[w]*NE + e];
        }
      }
    }
    // weight prep, grid-strided over all items
    for (int t0 = bid*256 + tid; t0 < SETUP_ITEMS; t0 += nblk*256) {
      int t = t0;
      if (t < N_BIAS) {
        int layer = t / BIAS4, i = t % BIAS4;
        const float* bs = layer==0 ? b0 : (layer==1 ? b1 : b2);
        float* hd = layer==0 ? h1 : (layer==1 ? h2 : h3);
        reinterpret_cast<float4*>(hd)[i] = reinterpret_cast<const float4*>(bs)[i % 150];
      } else if ((t -= N_BIAS) < NSWZ) {
        // Wbf[((r*20+nt)*10+ks)*64+lane)*8+j] = bf16(Wenc[r][f][e]),
        // f = nt*16+(lane&15), e = ks*32+(lane>>4)*8+j, zero-padded past 300.
        int lane = t & 63, rest = t >> 6;
        int ksi = rest % 10, rnt = rest / 10, nt = rnt % 20, r = rnt / 20;
        int f = nt*16 + (lane & 15), e0 = ksi*32 + (lane >> 4)*8;
        ushort v[8];
        #pragma unroll
        for (int j = 0; j < 8; j++) {
          int e = e0 + j;
          v[j] = (f < NE && e < NE) ? f2bf(Wenc[((size_t)r*NE + f)*NE + e]) : (ushort)0;
        }
        *reinterpret_cast<int4*>(&Wbf[(size_t)t*8]) = *reinterpret_cast<const int4*>(v);
      } else if ((t -= NSWZ) < NT0) {
        int k = t / 600, j = t % 600;
        W0T[t] = W0[(size_t)j*1800 + k];
      } else if ((t -= NT0) < NTH) {
        int k = t / 600, j = t % 600;
        W1T[t] = W1[(size_t)j*600 + k];
      } else {
        t -= NTH;
        int k = t / 600, j = t % 600;
        W2T[t] = W2[(size_t)j*600 + k];
      }
    }
  }
  grid.sync();

  // ===== Tree: level-synchronous bottom-up (dense: all children, 3 rel GEMMs)
  const int c0s[3] = {21, 5, 1};
  const int nls[3] = {43, 16, 4};
  const int p0s[3] = {5, 1, 0};
  const int nps[3] = {11, 4, 1};
  for (int li = 0; li < 3; li++) {
    // --- gemm phase: tiles of 32 rows; counts are exact multiples of 32 ---
    {
      ushort* A    = (ushort*)smem;              // 32 x 328
      int*   rcode = (int*)(smem + 20992);       // 32
      int*   srel  = rcode + 32;                 // 32
      int nl = nls[li], c0 = c0s[li];
      int ntiles = (2*NB*nl) >> 5;               // 688 / 256 / 64
      for (int tt = bid; tt < ntiles; tt += nblk) {
        if (tid < 32) {
          int idx = tt*32 + tid;
          int j = idx % nl, b = (idx/nl) % NB, s = idx/(nl*NB);
          int c = c0 + j;
          rcode[tid] = (s << 14) | (b << 6) | c;
          srel[tid]  = (s ? hrel : prel)[b*NN + c];
        }
        __syncthreads();
        for (int flat = tid; flat < 32*75; flat += 256) {
          int i = flat / 75, cc = flat % 75;
          int code = rcode[i];
          int cn = code & 63, bb = (code >> 6) & 255, s = code >> 14;
          const float4 v = *reinterpret_cast<const float4*>(
              &h[((size_t)(s*NB + bb)*NN + cn)*NE + cc*4]);
          ushort4 o; o.x = f2bf(v.x); o.y = f2bf(v.y); o.z = f2bf(v.z); o.w = f2bf(v.w);
          *reinterpret_cast<ushort4*>(&A[i*328 + cc*4]) = o;
        }
        for (int flat = tid; flat < 32*10; flat += 256) {
          int i = flat / 10, cc = flat % 10;
          *reinterpret_cast<unsigned*>(&A[i*328 + 300 + cc*2]) = 0u;
        }
        __syncthreads();
        int wave = tid >> 6, lane = tid & 63;
        int mrow = lane & 15, quad = lane >> 4;
        bf16x8 af[2][10];
        #pragma unroll
        for (int sub = 0; sub < 2; sub++)
          #pragma unroll
          for (int ks = 0; ks < 10; ks++)
            af[sub][ks] = *reinterpret_cast<const bf16x8*>(
                &A[(sub*16 + mrow)*328 + ks*32 + quad*8]);
        for (int r = 0; r < 3; r++) {
          f32x4 acc[5][2];
          #pragma unroll
          for (int a = 0; a < 5; a++)
            #pragma unroll
            for (int b2 = 0; b2 < 2; b2++) acc[a][b2] = f32x4{0.f,0.f,0.f,0.f};
          const ushort* Wb = Wbf + (size_t)r*12800*8;
          #pragma unroll
          for (int t5 = 0; t5 < 5; t5++) {
            int nt = wave + t5*4;
            #pragma unroll
            for (int ks = 0; ks < 10; ks++) {
              bf16x8 bf = *reinterpret_cast<const bf16x8*>(
                  &Wb[((size_t)(nt*10 + ks)*64 + lane)*8]);
              acc[t5][0] = __builtin_amdgcn_mfma_f32_16x16x32_bf16(af[0][ks], bf, acc[t5][0], 0, 0, 0);
              acc[t5][1] = __builtin_amdgcn_mfma_f32_16x16x32_bf16(af[1][ks], bf, acc[t5][1], 0, 0, 0);
            }
          }
          // epilogue: C/D col(n)=lane&15, row(m)=quad*4+reg; store only rel==r rows
          #pragma unroll
          for (int t5 = 0; t5 < 5; t5++) {
            int nt = wave + t5*4;
            int f = nt*16 + mrow;
            if (f < NE) {
              #pragma unroll
              for (int sub = 0; sub < 2; sub++) {
                #pragma unroll
                for (int reg = 0; reg < 4; reg++) {
                  int ml = sub*16 + quad*4 + reg;
                  if (srel[ml] == r) {
                    int code = rcode[ml];
                    int cn = code & 63, bb = (code >> 6) & 255, s = code >> 14;
                    T[((size_t)(s*NB + bb)*NN + cn)*NE + f] = acc[t5][sub][reg];
                  }
                }
              }
            }
          }
        }
        __syncthreads();
      }
    }
    grid.sync();
    // --- parent phase ---
    {
      int np = nps[li], p0 = p0s[li];
      int units = 2*NB*np;
      for (int u = bid; u < units; u += nblk) {
        int p = p0 + u % np;
        int b = (u/np) % NB, s = u/(np*NB);
        int nc = min(4, 63 - 4*p);   // parent 15 has 3 children
        const int* rel = (s ? hrel : prel) + b*NN;
        size_t hb = (size_t)(s*NB + b)*NN;
        float inv = 1.0f / (float)nc;
        for (int f = tid; f < NE; f += 256) {
          float sum = 0.f;
          for (int jj = 0; jj < nc; jj++) {
            int c = 4*p + 1 + jj;
            int r = rel[c];
            const float* src = (r >= 0 && r <= 2) ? T : h;
            sum += src[(hb + c)*NE + f];
          }
          float hp = h[(hb + p)*NE + f];
          float v = hp * sum * inv;
          h[(hb + p)*NE + f] = v > 0.f ? v : 0.f;
        }
      }
    }
    grid.sync();
  }

  // ===== MLP chain =====
  fc_phase(smem, tid, bid, nblk, nullptr, W0T, h1, 6*NE, 225, 8, 2, rep, h);
  grid.sync();
  fc_phase(smem, tid, bid, nblk, h1, W1T, h2, NH, 150, 4, 1, nullptr, nullptr);
  grid.sync();
  fc_phase(smem, tid, bid, nblk, h2, W2T, h3, NH, 150, 4, 1, nullptr, nullptr);
  grid.sync();

  // ===== output layer: one wave per batch row =====
  {
    int lane = tid & 63;
    for (int wid = bid*4 + (tid >> 6); wid < NB; wid += nblk*4) {
      float a0 = 0.f, a1 = 0.f, a2 = 0.f;
      for (int k = lane; k < NH; k += 64) {
        float xv = fmaxf(h3[(size_t)wid*NH + k], 0.f);
        a0 += xv * Wout[k];
        a1 += xv * Wout[NH + k];
        a2 += xv * Wout[2*NH + k];
      }
      #pragma unroll
      for (int off = 32; off > 0; off >>= 1) {
        a0 += __shfl_down(a0, off, 64);
        a1 += __shfl_down(a1, off, 64);
        a2 += __shfl_down(a2, off, 64);
      }
      if (lane == 0) {
        outp[wid*3 + 0] = a0 + bout[0];
        outp[wid*3 + 1] = a1 + bout[1];
        outp[wid*3 + 2] = a2 + bout[2];
      }
    }
  }
}

// ---------------- launch ----------------
extern "C" void kernel_launch(void* const* d_in, const int* in_sizes, int n_in,
                              void* d_out, int out_size, void* d_ws, size_t ws_size,
                              hipStream_t stream) {
  const int*   px    = (const int*)d_in[0];
  const int*   hx    = (const int*)d_in[1];
  const int*   pwi   = (const int*)d_in[2];
  const int*   prel  = (const int*)d_in[3];
  const int*   hwi   = (const int*)d_in[4];
  const int*   hrel  = (const int*)d_in[5];
  // d_in[6]=parent, d_in[7]=level: fixed 4-ary tree, hardcoded
  const float* Etab  = (const float*)d_in[8];
  const float* Wenc  = (const float*)d_in[9];
  const float* W0w   = (const float*)d_in[10];
  const float* W0b   = (const float*)d_in[11];
  const float* W1w   = (const float*)d_in[12];
  const float* W1b   = (const float*)d_in[13];
  const float* W2w   = (const float*)d_in[14];
  const float* W2b   = (const float*)d_in[15];
  const float* Woutw = (const float*)d_in[16];
  const float* Woutb = (const float*)d_in[17];
  float* ws   = (float*)d_ws;
  float* outp = (float*)d_out;

  // Ask the runtime how many blocks/CU are actually co-residentable and size
  // the cooperative grid from that (deterministic every call; host-only query,
  // graph-capture safe). 256 CUs on MI355X.
  int occ = 0;
  (void)hipOccupancyMaxActiveBlocksPerMultiprocessor(&occ, k_mega, 256, 0);
  if (occ < 1) occ = 1;
  if (occ > 2) occ = 2;
  int grid = 256 * occ;

  void* kargs[] = {
    (void*)&px, (void*)&hx, (void*)&pwi, (void*)&prel, (void*)&hwi, (void*)&hrel,
    (void*)&Etab, (void*)&Wenc, (void*)&W0w, (void*)&W0b, (void*)&W1w, (void*)&W1b,
    (void*)&W2w, (void*)&W2b, (void*)&Woutw, (void*)&Woutb, (void*)&ws, (void*)&outp
  };
  hipLaunchCooperativeKernel((void*)k_mega, dim3(grid), dim3(256), kargs, 0, stream);
}

// Round 7
// 470.280 us; speedup vs baseline: 2.1236x; 2.1236x over previous
//
#include <hip/hip_runtime.h>

constexpr int NB = 256;   // batch
constexpr int NS = 64;    // seq len
constexpr int NN = 64;    // tree nodes
constexpr int NE = 300;   // embedding dim
constexpr int NH = 600;   // hidden dim

typedef __attribute__((ext_vector_type(8))) short bf16x8;
typedef __attribute__((ext_vector_type(4))) float f32x4;

// ---------------- workspace layout (float-indexed) ----------------
constexpr size_t OFF_REP = 0;                           // [2][NB][NE]
constexpr size_t SZ_REP  = (size_t)2*NB*NE;
constexpr size_t OFF_ROOT= OFF_REP + SZ_REP;            // [2][NB][NE]
constexpr size_t OFF_WBF = OFF_ROOT + SZ_REP;           // W_enc bf16 B-frag swizzled
constexpr size_t SZ_WBF  = (size_t)3*20*10*64*8/2;      // 153,600 floats
constexpr size_t OFF_W0T = OFF_WBF + SZ_WBF;            // W0^T [1800][600]
constexpr size_t SZ_W0T  = (size_t)6*NE*NH;
constexpr size_t OFF_W1T = OFF_W0T + SZ_W0T;            // W1^T [600][600]
constexpr size_t SZ_WH   = (size_t)NH*NH;
constexpr size_t OFF_W2T = OFF_W1T + SZ_WH;             // W2^T [600][600]
constexpr size_t OFF_H1  = OFF_W2T + SZ_WH;             // [NB][NH]
constexpr size_t SZ_HB   = (size_t)NB*NH;
constexpr size_t OFF_H2  = OFF_H1 + SZ_HB;
constexpr size_t OFF_H3  = OFF_H2 + SZ_HB;

__device__ __forceinline__ ushort f2bf(float x) {
  unsigned u = __float_as_uint(x);
  unsigned r = (u + 0x7FFFu + ((u >> 16) & 1u)) >> 16;   // RNE
  return (ushort)r;
}
__device__ __forceinline__ float bf2f(ushort u) {
  return __uint_as_float(((unsigned)u) << 16);
}

// ---------------- k_setup: bias-init + Wbf swizzle + MLP weight transposes ---
constexpr int BIAS4 = NB*NH/4;            // 38400 float4 per layer
constexpr int NSWZ  = 3*20*10*64;         // 38400 lane-frags
constexpr int PREP_ITEMS  = 3*BIAS4 + NSWZ;                      // 153600
constexpr int PREP_BLOCKS = (PREP_ITEMS + 255)/256;              // 600
constexpr int TR_BLOCKS   = 57*19*3;                             // 3249
constexpr int SETUP_BLOCKS = PREP_BLOCKS + TR_BLOCKS;

__global__ __launch_bounds__(256)
void k_setup(const float* __restrict__ Wenc, const float* __restrict__ b0,
             const float* __restrict__ b1, const float* __restrict__ b2,
             const float* __restrict__ W0, const float* __restrict__ W1,
             const float* __restrict__ W2,
             float* __restrict__ h1, float* __restrict__ h2, float* __restrict__ h3,
             ushort* __restrict__ Wbf,
             float* __restrict__ W0T, float* __restrict__ W1T, float* __restrict__ W2T) {
  __shared__ float tile[32][33];
  if (blockIdx.x < PREP_BLOCKS) {
    int t = blockIdx.x*256 + threadIdx.x;
    if (t < 3*BIAS4) {
      int layer = t / BIAS4, i = t % BIAS4;
      const float* bs = layer==0 ? b0 : (layer==1 ? b1 : b2);
      float* hd = layer==0 ? h1 : (layer==1 ? h2 : h3);
      reinterpret_cast<float4*>(hd)[i] = reinterpret_cast<const float4*>(bs)[i % 150];
      return;
    }
    t -= 3*BIAS4;
    if (t < NSWZ) {
      // Wbf[(((r*20+nt)*10+ks)*64+lane)*8+j] = bf16(Wenc[r][f][e]),
      // f = nt*16+(lane&15), e = ks*32+(lane>>4)*8+j, zero-padded past 300.
      int lane = t & 63, rest = t >> 6;
      int ksi = rest % 10, rnt = rest / 10, nt = rnt % 20, r = rnt / 20;
      int f = nt*16 + (lane & 15), e0 = ksi*32 + (lane >> 4)*8;
      ushort v[8];
      #pragma unroll
      for (int j = 0; j < 8; j++) {
        int e = e0 + j;
        v[j] = (f < NE && e < NE) ? f2bf(Wenc[((size_t)r*NE + f)*NE + e]) : (ushort)0;
      }
      *reinterpret_cast<int4*>(&Wbf[(size_t)t*8]) = *reinterpret_cast<const int4*>(v);
    }
    return;
  }
  // transpose tiles (coalesced both sides)
  int idx = blockIdx.x - PREP_BLOCKS;
  int z = idx / (57*19), rem = idx % (57*19);
  int by = rem / 57, bx = rem % 57;
  const float* W = z==0 ? W0 : (z==1 ? W1 : W2);
  float* WT = z==0 ? W0T : (z==1 ? W1T : W2T);
  int K = z==0 ? 1800 : 600;               // W [600][K] -> WT [K][600]
  int k0 = bx * 32, j0 = by * 32;
  if (k0 >= K) return;
  int tx = threadIdx.x & 31, ty = threadIdx.x >> 5;
  for (int yy = ty; yy < 32; yy += 8) {
    int j = j0 + yy, k = k0 + tx;
    if (j < 600 && k < K) tile[yy][tx] = W[(size_t)j*K + k];
  }
  __syncthreads();
  for (int yy = ty; yy < 32; yy += 8) {
    int k = k0 + yy, j = j0 + tx;
    if (k < K && j < 600) WT[(size_t)k*600 + j] = tile[tx][yy];
  }
}

// ---------------- k_tree: whole tree for one (s,b) per block ----------------
// LDS: hS bf16 [64][328] (proven MFMA-A layout), Tb fp32 [16][306],
// index arrays. 5 parent-batches: level 3 = parents (5,4),(9,4),(13,3);
// level 2 = (1,4); level 1 = (0,1). Each batch: 1 M-tile x 3 relation GEMMs
// (MFMA 16x16x32 bf16), then parent update, all under __syncthreads.
constexpr int TS = 328;   // hS row stride (ushorts); 656B = 164 dwords = bank+4/row
constexpr int TTS = 306;  // Tb row stride (floats); 4*306 % 32 != 0

__global__ __launch_bounds__(320)
void k_tree(const int* __restrict__ px, const int* __restrict__ hx,
            const int* __restrict__ pwi, const int* __restrict__ prel,
            const int* __restrict__ hwi, const int* __restrict__ hrel,
            const float* __restrict__ Etab, const ushort* __restrict__ Wbf,
            float* __restrict__ rep, float* __restrict__ root) {
  __shared__ ushort hS[64*TS];        // 41,984 B
  __shared__ float  Tb[16*TTS];       // 19,584 B
  __shared__ int xsh[64];
  __shared__ int wish[64];
  __shared__ int relsh[64];
  const int sb = blockIdx.x;
  const int s = sb >> 8, b = sb & 255;
  const int tid = threadIdx.x;

  if (tid < 64) xsh[tid] = ((s ? hx : px) + b*NS)[tid];
  else if (tid < 128) wish[tid-64] = ((s ? hwi : pwi) + b*NN)[tid-64];
  else if (tid < 192) relsh[tid-128] = ((s ? hrel : prel) + b*NN)[tid-128];
  __syncthreads();

  // gather: rep = sum of 64 seq-embedding rows; hS[n] = bf16(word[n])
  if (tid < NE) {
    int e = tid;
    float acc = 0.f;
    #pragma unroll 8
    for (int j = 0; j < NS; j++) acc += Etab[(size_t)xsh[j]*NE + e];
    rep[(size_t)sb*NE + e] = acc;
    for (int n = 0; n < NN; n++) {
      int w = wish[n];
      float v = (w < 0) ? 1.0f : Etab[(size_t)xsh[w]*NE + e];
      hS[n*TS + e] = f2bf(v);
    }
  }
  // zero-pad K region e in [300,320) for all rows
  for (int z = tid; z < 64*10; z += 320) {
    int row = z / 10, cc = z % 10;
    *reinterpret_cast<unsigned*>(&hS[row*TS + 300 + cc*2]) = 0u;
  }
  __syncthreads();

  const int pb[5] = {5, 9, 13, 1, 0};
  const int pc[5] = {4, 4, 3, 4, 1};
  const int wave = tid >> 6, lane = tid & 63;
  const int mrow = lane & 15, quad = lane >> 4;

  #pragma unroll 1
  for (int bt = 0; bt < 5; bt++) {
    int pbase = pb[bt], pcount = pc[bt];
    int cbase = 4*pbase + 1;
    int ccount = 4*pcount - ((pbase + pcount > 15) ? 1 : 0);

    // ---- GEMM: A rows = hS[cbase+m] (m=lane&15, clamped), B = Wbf[r] ----
    int arow = min(cbase + mrow, 63);
    bf16x8 af[10];
    #pragma unroll
    for (int ks = 0; ks < 10; ks++)
      af[ks] = *reinterpret_cast<const bf16x8*>(&hS[arow*TS + ks*32 + quad*8]);

    #pragma unroll 1
    for (int r = 0; r < 3; r++) {
      f32x4 acc[4];
      #pragma unroll
      for (int t4 = 0; t4 < 4; t4++) acc[t4] = f32x4{0.f,0.f,0.f,0.f};
      const ushort* Wb = Wbf + (size_t)r*12800*8;
      #pragma unroll
      for (int t4 = 0; t4 < 4; t4++) {
        int nt = wave*4 + t4;            // 0..19; tile 19 is all-pad
        if (nt >= 19) continue;
        #pragma unroll
        for (int ks = 0; ks < 10; ks++) {
          bf16x8 bf = *reinterpret_cast<const bf16x8*>(
              &Wb[((size_t)(nt*10 + ks)*64 + lane)*8]);
          acc[t4] = __builtin_amdgcn_mfma_f32_16x16x32_bf16(af[ks], bf, acc[t4], 0, 0, 0);
        }
      }
      // epilogue: D col(f)=lane&15, row(m)=quad*4+reg (verified layout)
      #pragma unroll
      for (int t4 = 0; t4 < 4; t4++) {
        int nt = wave*4 + t4;
        if (nt >= 19) continue;
        int f = nt*16 + mrow;
        if (f < NE) {
          #pragma unroll
          for (int reg = 0; reg < 4; reg++) {
            int m = quad*4 + reg;
            if (m < ccount && relsh[cbase + m] == r)
              Tb[m*TTS + f] = acc[t4][reg];
          }
        }
      }
    }
    __syncthreads();

    // ---- parent update: h[p] = relu(word[p] * mean(children)) ----
    if (tid < NE) {
      int f = tid;
      for (int pi = 0; pi < pcount; pi++) {
        int p = pbase + pi;
        int nc = (p == 15) ? 3 : 4;
        float sum = 0.f;
        for (int j = 0; j < nc; j++) {
          int c = 4*p + 1 + j;
          int rr = relsh[c];
          float cv = (rr >= 0 && rr <= 2) ? Tb[(c - cbase)*TTS + f]
                                          : bf2f(hS[c*TS + f]);
          sum += cv;
        }
        float hp = bf2f(hS[p*TS + f]);
        float v = hp * sum * (1.0f / (float)nc);
        v = v > 0.f ? v : 0.f;
        hS[p*TS + f] = f2bf(v);
        if (p == 0) root[(size_t)sb*NE + f] = v;
      }
    }
    __syncthreads();
  }
}

// ---------------- k_fc: split-K FC partial ----------------
// block = 64b x 64j tile, thread = 4b x 4j, K-chunk per blockIdx.z.
// Partials atomicAdd onto bias-initialized out.
// mode 0/1: (relu) input; mode 2: build concat feature on the fly:
// x = [p_rep, h_rep, p-h, p*h, psg-hsg, psg*hsg] from rep/root.
__global__ __launch_bounds__(256)
void k_fc(const float* __restrict__ in, const float* __restrict__ WTm,
          float* __restrict__ out, int K, int kc, int mode,
          const float* __restrict__ rep, const float* __restrict__ root) {
  __shared__ __align__(16) float xl[225*68];
  int b0 = blockIdx.x * 64;
  int j0 = blockIdx.y * 64;
  int k0 = blockIdx.z * kc;
  int tid = threadIdx.x;
  if (mode == 2) {
    for (int flat = tid; flat < kc*64; flat += 256) {
      int bbp = flat / kc, k = flat % kc;
      int kg = k0 + k, seg = kg / NE, e = kg % NE;
      int b = b0 + bbp;
      float v;
      switch (seg) {
        case 0: v = rep[(size_t)b*NE + e]; break;
        case 1: v = rep[(size_t)(NB+b)*NE + e]; break;
        case 2: v = rep[(size_t)b*NE + e] - rep[(size_t)(NB+b)*NE + e]; break;
        case 3: v = rep[(size_t)b*NE + e] * rep[(size_t)(NB+b)*NE + e]; break;
        case 4: v = root[(size_t)b*NE + e] - root[(size_t)(NB+b)*NE + e]; break;
        default: v = root[(size_t)b*NE + e] * root[(size_t)(NB+b)*NE + e]; break;
      }
      xl[k*68 + bbp] = v;
    }
  } else {
    for (int flat = tid; flat < kc*64; flat += 256) {
      int bbp = flat / kc, k = flat % kc;
      float v = in[(size_t)(b0+bbp)*K + k0 + k];
      if (mode == 1) v = fmaxf(v, 0.f);
      xl[k*68 + bbp] = v;
    }
  }
  __syncthreads();
  int tj = tid & 15, tb = tid >> 4;
  int j = j0 + tj*4;
  if (j + 3 >= NH) return;
  float acc[4][4];
  #pragma unroll
  for (int a = 0; a < 4; a++)
    #pragma unroll
    for (int bq = 0; bq < 4; bq++) acc[a][bq] = 0.f;
  for (int k = 0; k < kc; k++) {
    const float4 w  = *reinterpret_cast<const float4*>(&WTm[(size_t)(k0+k)*NH + j]);
    const float4 xv = *reinterpret_cast<const float4*>(&xl[k*68 + tb*4]);
    acc[0][0] += xv.x*w.x; acc[0][1] += xv.x*w.y; acc[0][2] += xv.x*w.z; acc[0][3] += xv.x*w.w;
    acc[1][0] += xv.y*w.x; acc[1][1] += xv.y*w.y; acc[1][2] += xv.y*w.z; acc[1][3] += xv.y*w.w;
    acc[2][0] += xv.z*w.x; acc[2][1] += xv.z*w.y; acc[2][2] += xv.z*w.z; acc[2][3] += xv.z*w.w;
    acc[3][0] += xv.w*w.x; acc[3][1] += xv.w*w.y; acc[3][2] += xv.w*w.z; acc[3][3] += xv.w*w.w;
  }
  #pragma unroll
  for (int bi = 0; bi < 4; bi++)
    #pragma unroll
    for (int ji = 0; ji < 4; ji++)
      atomicAdd(&out[(size_t)(b0 + tb*4 + bi)*NH + j + ji], acc[bi][ji]);
}

// Final 600->3 layer; one wave per batch row; relu(h3) folded into load.
__global__ __launch_bounds__(64)
void k_out(const float* __restrict__ h3, const float* __restrict__ Wout,
           const float* __restrict__ bout, float* __restrict__ out) {
  int b = blockIdx.x, tid = threadIdx.x;
  float a0 = 0.f, a1 = 0.f, a2 = 0.f;
  for (int k = tid; k < NH; k += 64) {
    float xv = fmaxf(h3[(size_t)b*NH + k], 0.f);
    a0 += xv * Wout[k];
    a1 += xv * Wout[NH + k];
    a2 += xv * Wout[2*NH + k];
  }
  #pragma unroll
  for (int off = 32; off > 0; off >>= 1) {
    a0 += __shfl_down(a0, off, 64);
    a1 += __shfl_down(a1, off, 64);
    a2 += __shfl_down(a2, off, 64);
  }
  if (tid == 0) {
    out[b*3 + 0] = a0 + bout[0];
    out[b*3 + 1] = a1 + bout[1];
    out[b*3 + 2] = a2 + bout[2];
  }
}

// ---------------- launch ----------------
extern "C" void kernel_launch(void* const* d_in, const int* in_sizes, int n_in,
                              void* d_out, int out_size, void* d_ws, size_t ws_size,
                              hipStream_t stream) {
  const int*   px    = (const int*)d_in[0];
  const int*   hx    = (const int*)d_in[1];
  const int*   pwi   = (const int*)d_in[2];
  const int*   prel  = (const int*)d_in[3];
  const int*   hwi   = (const int*)d_in[4];
  const int*   hrel  = (const int*)d_in[5];
  // d_in[6]=parent, d_in[7]=level: fixed 4-ary tree, hardcoded
  const float* Etab  = (const float*)d_in[8];
  const float* Wenc  = (const float*)d_in[9];
  const float* W0w   = (const float*)d_in[10];
  const float* W0b   = (const float*)d_in[11];
  const float* W1w   = (const float*)d_in[12];
  const float* W1b   = (const float*)d_in[13];
  const float* W2w   = (const float*)d_in[14];
  const float* W2b   = (const float*)d_in[15];
  const float* Woutw = (const float*)d_in[16];
  const float* Woutb = (const float*)d_in[17];

  float* ws   = (float*)d_ws;
  float* rep  = ws + OFF_REP;
  float* root = ws + OFF_ROOT;
  ushort* Wbf = (ushort*)(ws + OFF_WBF);
  float* W0T  = ws + OFF_W0T;
  float* W1T  = ws + OFF_W1T;
  float* W2T  = ws + OFF_W2T;
  float* h1   = ws + OFF_H1;
  float* h2   = ws + OFF_H2;
  float* h3   = ws + OFF_H3;
  float* outp = (float*)d_out;

  dim3 blk(256);
  k_setup<<<dim3(SETUP_BLOCKS), blk, 0, stream>>>(
      Wenc, W0b, W1b, W2b, W0w, W1w, W2w, h1, h2, h3, Wbf, W0T, W1T, W2T);
  k_tree<<<dim3(2*NB), dim3(320), 0, stream>>>(
      px, hx, pwi, prel, hwi, hrel, Etab, Wbf, rep, root);
  k_fc<<<dim3(4, 10, 8), blk, 0, stream>>>(nullptr, W0T, h1, 6*NE, 225, 2, rep, root);
  k_fc<<<dim3(4, 10, 4), blk, 0, stream>>>(h1, W1T, h2, NH, 150, 1, nullptr, nullptr);
  k_fc<<<dim3(4, 10, 4), blk, 0, stream>>>(h2, W2T, h3, NH, 150, 1, nullptr, nullptr);
  k_out<<<dim3(NB), dim3(64), 0, stream>>>(h3, Woutw, Woutb, outp);
}

// Round 8
// 390.500 us; speedup vs baseline: 2.5574x; 1.2043x over previous
//
#include <hip/hip_runtime.h>

constexpr int NB = 256;   // batch
constexpr int NS = 64;    // seq len
constexpr int NN = 64;    // tree nodes
constexpr int NE = 300;   // embedding dim
constexpr int NH = 600;   // hidden dim

typedef __attribute__((ext_vector_type(8))) short bf16x8;
typedef __attribute__((ext_vector_type(4))) float f32x4;

// ---------------- workspace layout (float-indexed) ----------------
constexpr size_t OFF_REP = 0;                           // [2][NB][NE]
constexpr size_t SZ_REP  = (size_t)2*NB*NE;
constexpr size_t OFF_ROOT= OFF_REP + SZ_REP;            // [2][NB][NE]
constexpr size_t OFF_WBF = OFF_ROOT + SZ_REP;           // W_enc bf16 B-frag swizzled
constexpr size_t SZ_WBF  = (size_t)3*20*10*64*8/2;      // 153,600 floats
constexpr size_t OFF_W0T = OFF_WBF + SZ_WBF;            // W0^T [1800][600]
constexpr size_t SZ_W0T  = (size_t)6*NE*NH;
constexpr size_t OFF_W1T = OFF_W0T + SZ_W0T;            // W1^T [600][600]
constexpr size_t SZ_WH   = (size_t)NH*NH;
constexpr size_t OFF_W2T = OFF_W1T + SZ_WH;             // W2^T [600][600]
constexpr size_t OFF_H1  = OFF_W2T + SZ_WH;             // [NB][NH]
constexpr size_t SZ_HB   = (size_t)NB*NH;
constexpr size_t OFF_H2  = OFF_H1 + SZ_HB;
constexpr size_t OFF_H3  = OFF_H2 + SZ_HB;

__device__ __forceinline__ ushort f2bf(float x) {
  unsigned u = __float_as_uint(x);
  unsigned r = (u + 0x7FFFu + ((u >> 16) & 1u)) >> 16;   // RNE
  return (ushort)r;
}
__device__ __forceinline__ float bf2f(ushort u) {
  return __uint_as_float(((unsigned)u) << 16);
}

// ---------------- k_setup: bias-init + Wbf swizzle + MLP weight transposes ---
constexpr int BIAS4 = NB*NH/4;            // 38400 float4 per layer
constexpr int NSWZ  = 3*20*10*64;         // 38400 lane-frags
constexpr int PREP_ITEMS  = 3*BIAS4 + NSWZ;                      // 153600
constexpr int PREP_BLOCKS = (PREP_ITEMS + 255)/256;              // 600
constexpr int TR_BLOCKS   = 57*19*3;                             // 3249
constexpr int SETUP_BLOCKS = PREP_BLOCKS + TR_BLOCKS;

__global__ __launch_bounds__(256)
void k_setup(const float* __restrict__ Wenc, const float* __restrict__ b0,
             const float* __restrict__ b1, const float* __restrict__ b2,
             const float* __restrict__ W0, const float* __restrict__ W1,
             const float* __restrict__ W2,
             float* __restrict__ h1, float* __restrict__ h2, float* __restrict__ h3,
             ushort* __restrict__ Wbf,
             float* __restrict__ W0T, float* __restrict__ W1T, float* __restrict__ W2T) {
  __shared__ float tile[32][33];
  if (blockIdx.x < PREP_BLOCKS) {
    int t = blockIdx.x*256 + threadIdx.x;
    if (t < 3*BIAS4) {
      int layer = t / BIAS4, i = t % BIAS4;
      const float* bs = layer==0 ? b0 : (layer==1 ? b1 : b2);
      float* hd = layer==0 ? h1 : (layer==1 ? h2 : h3);
      reinterpret_cast<float4*>(hd)[i] = reinterpret_cast<const float4*>(bs)[i % 150];
      return;
    }
    t -= 3*BIAS4;
    if (t < NSWZ) {
      // Wbf[(((r*20+nt)*10+ks)*64+lane)*8+j] = bf16(Wenc[r][f][e]),
      // f = nt*16+(lane&15), e = ks*32+(lane>>4)*8+j, zero-padded past 300.
      int lane = t & 63, rest = t >> 6;
      int ksi = rest % 10, rnt = rest / 10, nt = rnt % 20, r = rnt / 20;
      int f = nt*16 + (lane & 15), e0 = ksi*32 + (lane >> 4)*8;
      ushort v[8];
      #pragma unroll
      for (int j = 0; j < 8; j++) {
        int e = e0 + j;
        v[j] = (f < NE && e < NE) ? f2bf(Wenc[((size_t)r*NE + f)*NE + e]) : (ushort)0;
      }
      *reinterpret_cast<int4*>(&Wbf[(size_t)t*8]) = *reinterpret_cast<const int4*>(v);
    }
    return;
  }
  // transpose tiles (coalesced both sides)
  int idx = blockIdx.x - PREP_BLOCKS;
  int z = idx / (57*19), rem = idx % (57*19);
  int by = rem / 57, bx = rem % 57;
  const float* W = z==0 ? W0 : (z==1 ? W1 : W2);
  float* WT = z==0 ? W0T : (z==1 ? W1T : W2T);
  int K = z==0 ? 1800 : 600;               // W [600][K] -> WT [K][600]
  int k0 = bx * 32, j0 = by * 32;
  if (k0 >= K) return;
  int tx = threadIdx.x & 31, ty = threadIdx.x >> 5;
  for (int yy = ty; yy < 32; yy += 8) {
    int j = j0 + yy, k = k0 + tx;
    if (j < 600 && k < K) tile[yy][tx] = W[(size_t)j*K + k];
  }
  __syncthreads();
  for (int yy = ty; yy < 32; yy += 8) {
    int k = k0 + yy, j = j0 + tx;
    if (k < K && j < 600) WT[(size_t)k*600 + j] = tile[tx][yy];
  }
}

// ---------------- k_tree: whole tree for one (s,b) per block ----------------
// hS bf16 [64][328] (MFMA-A layout). 3 phases: L3 (children 21..63, 3 M-tiles,
// af[3][10] in regs so each B-frag feeds 3 MFMAs), L2 (5..20), L1 (1..4).
// Transform t written IN PLACE (bf16) over the child's hS row; parent update
// then reads hS uniformly (t if rel in 0..2, else word).
constexpr int TS = 328;   // row stride (ushorts): 656B -> 2-way bank alias (free)

__global__ __launch_bounds__(256)
void k_tree(const int* __restrict__ px, const int* __restrict__ hx,
            const int* __restrict__ pwi, const int* __restrict__ prel,
            const int* __restrict__ hwi, const int* __restrict__ hrel,
            const float* __restrict__ Etab, const ushort* __restrict__ Wbf,
            float* __restrict__ rep, float* __restrict__ root) {
  __shared__ __align__(16) ushort hS[64*TS];   // 41,984 B
  __shared__ int xsh[64];
  __shared__ int wish[64];
  __shared__ int relsh[64];
  const int sb = blockIdx.x;
  const int s = sb >> 8, b = sb & 255;
  const int tid = threadIdx.x;

  if (tid < 64) xsh[tid] = ((s ? hx : px) + b*NS)[tid];
  else if (tid < 128) wish[tid-64] = ((s ? hwi : pwi) + b*NN)[tid-64];
  else if (tid < 192) relsh[tid-128] = ((s ? hrel : prel) + b*NN)[tid-128];
  __syncthreads();

  // rep = sum of 64 seq-embedding rows (coalesced, unroll-8 for ILP)
  for (int e = tid; e < NE; e += 256) {
    float acc = 0.f;
    #pragma unroll 8
    for (int j = 0; j < NS; j++) acc += Etab[(size_t)xsh[j]*NE + e];
    rep[(size_t)sb*NE + e] = acc;
  }
  // word build: flat float4 loop, 4800 independent chunks (good MLP)
  for (int flat = tid; flat < 64*75; flat += 256) {
    int n = flat / 75, c = flat % 75;
    int w = wish[n];
    float4 v;
    if (w < 0) v = float4{1.f,1.f,1.f,1.f};
    else v = *reinterpret_cast<const float4*>(&Etab[(size_t)xsh[w]*NE + c*4]);
    ushort4 o; o.x = f2bf(v.x); o.y = f2bf(v.y); o.z = f2bf(v.z); o.w = f2bf(v.w);
    *reinterpret_cast<ushort4*>(&hS[n*TS + c*4]) = o;
  }
  // zero-pad K region e in [300,320)
  for (int z = tid; z < 64*10; z += 256) {
    int row = z / 10, cc = z % 10;
    *reinterpret_cast<unsigned*>(&hS[row*TS + 300 + cc*2]) = 0u;
  }
  __syncthreads();

  const int wave = tid >> 6, lane = tid & 63;
  const int mrow = lane & 15, quad = lane >> 4;

  // ===== Phase L3: children 21..63 (M-tiles at 21/37/53), parents 5..15 =====
  {
    const int mb0 = 21, mb1 = 37, mb2 = 53;
    bf16x8 af[3][10];
    #pragma unroll
    for (int ks = 0; ks < 10; ks++) {
      af[0][ks] = *reinterpret_cast<const bf16x8*>(&hS[(mb0+mrow)*TS + ks*32 + quad*8]);
      af[1][ks] = *reinterpret_cast<const bf16x8*>(&hS[(mb1+mrow)*TS + ks*32 + quad*8]);
      int r2 = min(mb2+mrow, 63);
      af[2][ks] = *reinterpret_cast<const bf16x8*>(&hS[r2*TS + ks*32 + quad*8]);
    }
    __syncthreads();   // all af registered before in-place overwrite
    for (int pr = wave; pr < 57; pr += 4) {
      int r = pr / 19, nt = pr % 19;
      const ushort* Wb = &Wbf[(size_t)((r*20 + nt)*10)*64*8];
      f32x4 acc0 = f32x4{0.f,0.f,0.f,0.f};
      f32x4 acc1 = f32x4{0.f,0.f,0.f,0.f};
      f32x4 acc2 = f32x4{0.f,0.f,0.f,0.f};
      #pragma unroll
      for (int ks = 0; ks < 10; ks++) {
        bf16x8 bf = *reinterpret_cast<const bf16x8*>(&Wb[((size_t)ks*64 + lane)*8]);
        acc0 = __builtin_amdgcn_mfma_f32_16x16x32_bf16(af[0][ks], bf, acc0, 0, 0, 0);
        acc1 = __builtin_amdgcn_mfma_f32_16x16x32_bf16(af[1][ks], bf, acc1, 0, 0, 0);
        acc2 = __builtin_amdgcn_mfma_f32_16x16x32_bf16(af[2][ks], bf, acc2, 0, 0, 0);
      }
      int f = nt*16 + mrow;
      if (f < NE) {
        #pragma unroll
        for (int reg = 0; reg < 4; reg++) {
          int m = quad*4 + reg;
          int c0 = mb0 + m, c1 = mb1 + m, c2 = mb2 + m;
          if (relsh[c0] == r) hS[c0*TS + f] = f2bf(acc0[reg]);
          if (relsh[c1] == r) hS[c1*TS + f] = f2bf(acc1[reg]);
          if (c2 < 64 && relsh[c2] == r) hS[c2*TS + f] = f2bf(acc2[reg]);
        }
      }
    }
    __syncthreads();
    // parent update 5..15 (rows disjoint from children 21..63)
    for (int f = tid; f < NE; f += 256) {
      #pragma unroll
      for (int p = 5; p <= 15; p++) {
        int nc = (p == 15) ? 3 : 4;
        float sum = 0.f;
        for (int j = 0; j < nc; j++) sum += bf2f(hS[(4*p+1+j)*TS + f]);
        float v = bf2f(hS[p*TS + f]) * sum * (1.0f/(float)nc);
        hS[p*TS + f] = f2bf(v > 0.f ? v : 0.f);
      }
    }
    __syncthreads();
  }

  // ===== Phase L2: children 5..20 (one M-tile), parents 1..4 =====
  {
    bf16x8 af[10];
    #pragma unroll
    for (int ks = 0; ks < 10; ks++)
      af[ks] = *reinterpret_cast<const bf16x8*>(&hS[(5+mrow)*TS + ks*32 + quad*8]);
    __syncthreads();
    for (int pr = wave; pr < 57; pr += 4) {
      int r = pr / 19, nt = pr % 19;
      const ushort* Wb = &Wbf[(size_t)((r*20 + nt)*10)*64*8];
      f32x4 acc = f32x4{0.f,0.f,0.f,0.f};
      #pragma unroll
      for (int ks = 0; ks < 10; ks++) {
        bf16x8 bf = *reinterpret_cast<const bf16x8*>(&Wb[((size_t)ks*64 + lane)*8]);
        acc = __builtin_amdgcn_mfma_f32_16x16x32_bf16(af[ks], bf, acc, 0, 0, 0);
      }
      int f = nt*16 + mrow;
      if (f < NE) {
        #pragma unroll
        for (int reg = 0; reg < 4; reg++) {
          int c = 5 + quad*4 + reg;
          if (relsh[c] == r) hS[c*TS + f] = f2bf(acc[reg]);
        }
      }
    }
    __syncthreads();
    for (int f = tid; f < NE; f += 256) {
      #pragma unroll
      for (int p = 1; p <= 4; p++) {
        float sum = 0.f;
        #pragma unroll
        for (int j = 0; j < 4; j++) sum += bf2f(hS[(4*p+1+j)*TS + f]);
        float v = bf2f(hS[p*TS + f]) * sum * 0.25f;
        hS[p*TS + f] = f2bf(v > 0.f ? v : 0.f);
      }
    }
    __syncthreads();
  }

  // ===== Phase L1: children 1..4, parent 0 (root) =====
  {
    bool rp0 = (relsh[1]==0)|(relsh[2]==0)|(relsh[3]==0)|(relsh[4]==0);
    bool rp1 = (relsh[1]==1)|(relsh[2]==1)|(relsh[3]==1)|(relsh[4]==1);
    bool rp2 = (relsh[1]==2)|(relsh[2]==2)|(relsh[3]==2)|(relsh[4]==2);
    bf16x8 af[10];
    #pragma unroll
    for (int ks = 0; ks < 10; ks++)
      af[ks] = *reinterpret_cast<const bf16x8*>(&hS[(1+min(mrow,3))*TS + ks*32 + quad*8]);
    __syncthreads();
    for (int pr = wave; pr < 57; pr += 4) {
      int r = pr / 19, nt = pr % 19;
      if ((r==0 && !rp0) || (r==1 && !rp1) || (r==2 && !rp2)) continue;
      const ushort* Wb = &Wbf[(size_t)((r*20 + nt)*10)*64*8];
      f32x4 acc = f32x4{0.f,0.f,0.f,0.f};
      #pragma unroll
      for (int ks = 0; ks < 10; ks++) {
        bf16x8 bf = *reinterpret_cast<const bf16x8*>(&Wb[((size_t)ks*64 + lane)*8]);
        acc = __builtin_amdgcn_mfma_f32_16x16x32_bf16(af[ks], bf, acc, 0, 0, 0);
      }
      int f = nt*16 + mrow;
      if (f < NE) {
        #pragma unroll
        for (int reg = 0; reg < 4; reg++) {
          int m = quad*4 + reg;
          if (m < 4 && relsh[1+m] == r) hS[(1+m)*TS + f] = f2bf(acc[reg]);
        }
      }
    }
    __syncthreads();
    for (int f = tid; f < NE; f += 256) {
      float sum = 0.f;
      #pragma unroll
      for (int c = 1; c <= 4; c++) sum += bf2f(hS[c*TS + f]);
      float v = bf2f(hS[0*TS + f]) * sum * 0.25f;
      root[(size_t)sb*NE + f] = v > 0.f ? v : 0.f;
    }
  }
}

// ---------------- k_fc: split-K FC partial ----------------
// block = 64b x 64j tile, thread = 4b x 4j, K-chunk per blockIdx.z.
// Partials atomicAdd onto bias-initialized out.
// mode 0/1: (relu) input; mode 2: build concat feature on the fly:
// x = [p_rep, h_rep, p-h, p*h, psg-hsg, psg*hsg] from rep/root.
__global__ __launch_bounds__(256)
void k_fc(const float* __restrict__ in, const float* __restrict__ WTm,
          float* __restrict__ out, int K, int kc, int mode,
          const float* __restrict__ rep, const float* __restrict__ root) {
  __shared__ __align__(16) float xl[150*68];
  int b0 = blockIdx.x * 64;
  int j0 = blockIdx.y * 64;
  int k0 = blockIdx.z * kc;
  int tid = threadIdx.x;
  if (mode == 2) {
    for (int flat = tid; flat < kc*64; flat += 256) {
      int bbp = flat / kc, k = flat % kc;
      int kg = k0 + k, seg = kg / NE, e = kg % NE;
      int b = b0 + bbp;
      float v;
      switch (seg) {
        case 0: v = rep[(size_t)b*NE + e]; break;
        case 1: v = rep[(size_t)(NB+b)*NE + e]; break;
        case 2: v = rep[(size_t)b*NE + e] - rep[(size_t)(NB+b)*NE + e]; break;
        case 3: v = rep[(size_t)b*NE + e] * rep[(size_t)(NB+b)*NE + e]; break;
        case 4: v = root[(size_t)b*NE + e] - root[(size_t)(NB+b)*NE + e]; break;
        default: v = root[(size_t)b*NE + e] * root[(size_t)(NB+b)*NE + e]; break;
      }
      xl[k*68 + bbp] = v;
    }
  } else {
    for (int flat = tid; flat < kc*64; flat += 256) {
      int bbp = flat / kc, k = flat % kc;
      float v = in[(size_t)(b0+bbp)*K + k0 + k];
      if (mode == 1) v = fmaxf(v, 0.f);
      xl[k*68 + bbp] = v;
    }
  }
  __syncthreads();
  int tj = tid & 15, tb = tid >> 4;
  int j = j0 + tj*4;
  if (j + 3 >= NH) return;
  float acc[4][4];
  #pragma unroll
  for (int a = 0; a < 4; a++)
    #pragma unroll
    for (int bq = 0; bq < 4; bq++) acc[a][bq] = 0.f;
  for (int k = 0; k < kc; k++) {
    const float4 w  = *reinterpret_cast<const float4*>(&WTm[(size_t)(k0+k)*NH + j]);
    const float4 xv = *reinterpret_cast<const float4*>(&xl[k*68 + tb*4]);
    acc[0][0] += xv.x*w.x; acc[0][1] += xv.x*w.y; acc[0][2] += xv.x*w.z; acc[0][3] += xv.x*w.w;
    acc[1][0] += xv.y*w.x; acc[1][1] += xv.y*w.y; acc[1][2] += xv.y*w.z; acc[1][3] += xv.y*w.w;
    acc[2][0] += xv.z*w.x; acc[2][1] += xv.z*w.y; acc[2][2] += xv.z*w.z; acc[2][3] += xv.z*w.w;
    acc[3][0] += xv.w*w.x; acc[3][1] += xv.w*w.y; acc[3][2] += xv.w*w.z; acc[3][3] += xv.w*w.w;
  }
  #pragma unroll
  for (int bi = 0; bi < 4; bi++)
    #pragma unroll
    for (int ji = 0; ji < 4; ji++)
      atomicAdd(&out[(size_t)(b0 + tb*4 + bi)*NH + j + ji], acc[bi][ji]);
}

// Final 600->3 layer; one wave per batch row; relu(h3) folded into load.
__global__ __launch_bounds__(64)
void k_out(const float* __restrict__ h3, const float* __restrict__ Wout,
           const float* __restrict__ bout, float* __restrict__ out) {
  int b = blockIdx.x, tid = threadIdx.x;
  float a0 = 0.f, a1 = 0.f, a2 = 0.f;
  for (int k = tid; k < NH; k += 64) {
    float xv = fmaxf(h3[(size_t)b*NH + k], 0.f);
    a0 += xv * Wout[k];
    a1 += xv * Wout[NH + k];
    a2 += xv * Wout[2*NH + k];
  }
  #pragma unroll
  for (int off = 32; off > 0; off >>= 1) {
    a0 += __shfl_down(a0, off, 64);
    a1 += __shfl_down(a1, off, 64);
    a2 += __shfl_down(a2, off, 64);
  }
  if (tid == 0) {
    out[b*3 + 0] = a0 + bout[0];
    out[b*3 + 1] = a1 + bout[1];
    out[b*3 + 2] = a2 + bout[2];
  }
}

// ---------------- launch ----------------
extern "C" void kernel_launch(void* const* d_in, const int* in_sizes, int n_in,
                              void* d_out, int out_size, void* d_ws, size_t ws_size,
                              hipStream_t stream) {
  const int*   px    = (const int*)d_in[0];
  const int*   hx    = (const int*)d_in[1];
  const int*   pwi   = (const int*)d_in[2];
  const int*   prel  = (const int*)d_in[3];
  const int*   hwi   = (const int*)d_in[4];
  const int*   hrel  = (const int*)d_in[5];
  // d_in[6]=parent, d_in[7]=level: fixed 4-ary tree, hardcoded
  const float* Etab  = (const float*)d_in[8];
  const float* Wenc  = (const float*)d_in[9];
  const float* W0w   = (const float*)d_in[10];
  const float* W0b   = (const float*)d_in[11];
  const float* W1w   = (const float*)d_in[12];
  const float* W1b   = (const float*)d_in[13];
  const float* W2w   = (const float*)d_in[14];
  const float* W2b   = (const float*)d_in[15];
  const float* Woutw = (const float*)d_in[16];
  const float* Woutb = (const float*)d_in[17];

  float* ws   = (float*)d_ws;
  float* rep  = ws + OFF_REP;
  float* root = ws + OFF_ROOT;
  ushort* Wbf = (ushort*)(ws + OFF_WBF);
  float* W0T  = ws + OFF_W0T;
  float* W1T  = ws + OFF_W1T;
  float* W2T  = ws + OFF_W2T;
  float* h1   = ws + OFF_H1;
  float* h2   = ws + OFF_H2;
  float* h3   = ws + OFF_H3;
  float* outp = (float*)d_out;

  dim3 blk(256);
  k_setup<<<dim3(SETUP_BLOCKS), blk, 0, stream>>>(
      Wenc, W0b, W1b, W2b, W0w, W1w, W2w, h1, h2, h3, Wbf, W0T, W1T, W2T);
  k_tree<<<dim3(2*NB), blk, 0, stream>>>(
      px, hx, pwi, prel, hwi, hrel, Etab, Wbf, rep, root);
  k_fc<<<dim3(4, 10, 12), blk, 0, stream>>>(nullptr, W0T, h1, 6*NE, 150, 2, rep, root);
  k_fc<<<dim3(4, 10, 8), blk, 0, stream>>>(h1, W1T, h2, NH, 75, 1, nullptr, nullptr);
  k_fc<<<dim3(4, 10, 8), blk, 0, stream>>>(h2, W2T, h3, NH, 75, 1, nullptr, nullptr);
  k_out<<<dim3(NB), dim3(64), 0, stream>>>(h3, Woutw, Woutb, outp);
}